// Round 15
// baseline (239.829 us; speedup 1.0000x reference)
//
#include <hip/hip_runtime.h>

#define N_NODES 100000
#define N_EDGES 1600000
#define D 128

#define NSLOT   48    // ints per node region (192B, 16B-aligned); [0]=cnt, [4..47]=srcs
#define CAP     44    // P(Poisson(16) > 44) ~ 1e-12 per node; ovf list covers the rest
#define OVF_MAX 4096

typedef unsigned short ushort_t;
struct ushort4_t { ushort_t x, y, z, w; };
typedef __attribute__((ext_vector_type(8))) short bf16x8;
typedef __attribute__((ext_vector_type(4))) float f32x4;
typedef float vf4 __attribute__((ext_vector_type(4)));
typedef short vs4 __attribute__((ext_vector_type(4)));
typedef int vi4 __attribute__((ext_vector_type(4)));

#define NB_EDGE (N_EDGES / 256)           // 6250
#define NB_WBF  16
#define NB_LN   (N_NODES / 8)             // 12500

__device__ __forceinline__ ushort_t f2bf(float f) {
    unsigned u = __float_as_uint(f);
    unsigned r = (u + 0x7fffu + ((u >> 16) & 1u)) >> 16;   // RNE
    return (ushort_t)r;
}
__device__ __forceinline__ float bf2f(ushort_t b) {
    return __uint_as_float(((unsigned)b) << 16);
}

// ---------------- K1: bucket scatter (inline cnt) | wbf | LayerNorm+ReLU ---------
// One random line touch per edge (atomic + same-line store). 19.2MB bucket is
// L2-resident; hb stores are NT so LN traffic doesn't evict hot bucket lines.
__global__ __launch_bounds__(256) void build_wbf_ln_kernel(
    const void* __restrict__ e_raw, int* __restrict__ bucket,
    int* __restrict__ ovf, int* __restrict__ ovf_cnt,
    const float* __restrict__ W, ushort_t* __restrict__ wbf,
    const float* __restrict__ x, const float* __restrict__ gamma,
    const float* __restrict__ beta, ushort_t* __restrict__ hb)
{
    int b = blockIdx.x;
    if (b < NB_EDGE) {
        // inline int64-vs-int32 detect: odd int32 words of first 64 entries all 0
        int li = threadIdx.x & 63;
        int probe = ((const int*)e_raw)[2 * li + 1];
        bool is64 = (__ballot(probe == 0) == ~0ULL);   // wave-uniform

        int e = b * 256 + threadIdx.x;                 // exactly N_EDGES threads
        int s, d;
        if (is64) {
            s = (int)__builtin_nontemporal_load(&((const long long*)e_raw)[e]);
            d = (int)__builtin_nontemporal_load(&((const long long*)e_raw)[N_EDGES + e]);
        } else {
            s = __builtin_nontemporal_load(&((const int*)e_raw)[e]);
            d = __builtin_nontemporal_load(&((const int*)e_raw)[N_EDGES + e]);
        }
        int* reg = bucket + (size_t)d * NSLOT;
        int pos = atomicAdd(reg, 1);
        if (pos < CAP) {
            reg[4 + pos] = s;                          // same/adjacent hot line
        } else {
            int op = atomicAdd(ovf_cnt, 1);            // essentially never
            if (op < OVF_MAX) { ovf[op * 2] = d; ovf[op * 2 + 1] = s; }
        }
    } else if (b < NB_EDGE + NB_WBF) {
        // wbf: W -> bf16, 16 blocks cover 128*128
        int i = ((b - NB_EDGE) * 256 + threadIdx.x) * 4;
        float4 w = *(const float4*)(W + i);
        vs4 o;
        o[0] = (short)f2bf(w.x); o[1] = (short)f2bf(w.y);
        o[2] = (short)f2bf(w.z); o[3] = (short)f2bf(w.w);
        __builtin_nontemporal_store(o, (vs4*)(wbf + i));
    } else {
        int wave   = threadIdx.x >> 6;
        int half   = (threadIdx.x >> 5) & 1;
        int lane32 = threadIdx.x & 31;
        int row = (b - NB_EDGE - NB_WBF) * 8 + wave * 2 + half;
        float4 v = ((const float4*)(x + (size_t)row * D))[lane32];
        float s  = (v.x + v.y) + (v.z + v.w);
        float sq = (v.x * v.x + v.y * v.y) + (v.z * v.z + v.w * v.w);
#pragma unroll
        for (int m = 16; m >= 1; m >>= 1) {
            s  += __shfl_xor(s, m);
            sq += __shfl_xor(sq, m);
        }
        float mu   = s * (1.0f / D);
        float var  = sq * (1.0f / D) - mu * mu;
        float rstd = rsqrtf(var + 1e-5f);
        float4 g = ((const float4*)gamma)[lane32];
        float4 bb = ((const float4*)beta)[lane32];
        vs4 o;
        o[0] = (short)f2bf(fmaxf(fmaf((v.x - mu) * rstd, g.x, bb.x), 0.0f));
        o[1] = (short)f2bf(fmaxf(fmaf((v.y - mu) * rstd, g.y, bb.y), 0.0f));
        o[2] = (short)f2bf(fmaxf(fmaf((v.z - mu) * rstd, g.z, bb.z), 0.0f));
        o[3] = (short)f2bf(fmaxf(fmaf((v.w - mu) * rstd, g.w, bb.w), 0.0f));
        __builtin_nontemporal_store(o, (vs4*)(hb + (size_t)row * D + lane32 * 4));
    }
}

// ---------------- K2: bucket segment sum — one wave per node, bf16 out -----------
// Node n: deg = bucket[n*48], srcs = bucket[n*48+4 ..], data 16B-aligned.
__global__ __launch_bounds__(256) void bucket_segsum_kernel(
    const ushort_t* __restrict__ hb, const int* __restrict__ bucket,
    const int* __restrict__ ovf, const int* __restrict__ ovf_cnt,
    ushort_t* __restrict__ aggrb)
{
    int n    = blockIdx.x * 4 + (threadIdx.x >> 6);
    int lane = threadIdx.x & 63;
    const int* reg = bucket + (size_t)n * NSLOT;
    int deg  = reg[0];
    int eend = deg < CAP ? deg : CAP;
    const int* seg = reg + 4;
    const unsigned* hrow = (const unsigned*)hb;   // 64 dwords per node row
    float ax = 0.0f, ay = 0.0f;
    int e = 0;

    for (; e + 8 <= eend; e += 8) {
        vi4 sa = __builtin_nontemporal_load((const vi4*)(seg + e));
        vi4 sb = __builtin_nontemporal_load((const vi4*)(seg + e + 4));
        unsigned p0 = hrow[(size_t)sa[0] * 64 + lane];
        unsigned p1 = hrow[(size_t)sa[1] * 64 + lane];
        unsigned p2 = hrow[(size_t)sa[2] * 64 + lane];
        unsigned p3 = hrow[(size_t)sa[3] * 64 + lane];
        unsigned p4 = hrow[(size_t)sb[0] * 64 + lane];
        unsigned p5 = hrow[(size_t)sb[1] * 64 + lane];
        unsigned p6 = hrow[(size_t)sb[2] * 64 + lane];
        unsigned p7 = hrow[(size_t)sb[3] * 64 + lane];
        ax += bf2f((ushort_t)(p0 & 0xffffu)) + bf2f((ushort_t)(p1 & 0xffffu))
            + bf2f((ushort_t)(p2 & 0xffffu)) + bf2f((ushort_t)(p3 & 0xffffu))
            + bf2f((ushort_t)(p4 & 0xffffu)) + bf2f((ushort_t)(p5 & 0xffffu))
            + bf2f((ushort_t)(p6 & 0xffffu)) + bf2f((ushort_t)(p7 & 0xffffu));
        ay += bf2f((ushort_t)(p0 >> 16)) + bf2f((ushort_t)(p1 >> 16))
            + bf2f((ushort_t)(p2 >> 16)) + bf2f((ushort_t)(p3 >> 16))
            + bf2f((ushort_t)(p4 >> 16)) + bf2f((ushort_t)(p5 >> 16))
            + bf2f((ushort_t)(p6 >> 16)) + bf2f((ushort_t)(p7 >> 16));
    }
    for (; e < eend; ++e) {
        int s = seg[e];
        unsigned p = hrow[(size_t)s * 64 + lane];
        ax += bf2f((ushort_t)(p & 0xffffu));
        ay += bf2f((ushort_t)(p >> 16));
    }

    // overflow entries (count ~0; wave-uniform branch)
    int oc = *ovf_cnt;
    if (oc > 0) {
        oc = oc < OVF_MAX ? oc : OVF_MAX;
        for (int i = 0; i < oc; ++i) {
            if (ovf[2 * i] == n) {
                unsigned p = hrow[(size_t)ovf[2 * i + 1] * 64 + lane];
                ax += bf2f((ushort_t)(p & 0xffffu));
                ay += bf2f((ushort_t)(p >> 16));
            }
        }
    }

    unsigned o = (unsigned)f2bf(ax) | ((unsigned)f2bf(ay) << 16);
    __builtin_nontemporal_store(o, (unsigned*)aggrb + (size_t)n * 64 + lane);
}

// ---------------- K3: out = ((1+eps)h + aggr) @ W^T + b + x  (MFMA, swapped) -----
// mfma(W_frag, T_frag) -> lane (l16,kg) holds node row l16, cols nt*16+kg*4+(0..3)
__global__ __launch_bounds__(256) void gemm_mfma_kernel(
    const ushort_t* __restrict__ hb, const ushort_t* __restrict__ aggrb,
    const float* __restrict__ x, const ushort_t* __restrict__ wbf,
    const float* __restrict__ bias, const float* __restrict__ eps_p,
    float* __restrict__ out)
{
    const int wv   = threadIdx.x >> 6;
    const int lane = threadIdx.x & 63;
    const int l16  = lane & 15;
    const int kg   = lane >> 4;                 // 0..3
    const int node = blockIdx.x * 64 + wv * 16 + l16;
    const int rowc = node < N_NODES ? node : N_NODES - 1;
    const float ep1 = 1.0f + eps_p[0];

    f32x4 acc[8];
#pragma unroll
    for (int nt = 0; nt < 8; ++nt) acc[nt] = (f32x4){0.f, 0.f, 0.f, 0.f};

#pragma unroll
    for (int ks = 0; ks < 4; ++ks) {
        const int k0 = ks * 32 + kg * 8;
        const ushort_t* hp = hb    + (size_t)rowc * D + k0;
        const ushort_t* ap = aggrb + (size_t)rowc * D + k0;
        ushort4_t h0 = *(const ushort4_t*)(hp);
        ushort4_t h1 = *(const ushort4_t*)(hp + 4);
        ushort4_t a0 = *(const ushort4_t*)(ap);
        ushort4_t a1 = *(const ushort4_t*)(ap + 4);
        bf16x8 af;
        af[0] = (short)f2bf(fmaf(ep1, bf2f(h0.x), bf2f(a0.x)));
        af[1] = (short)f2bf(fmaf(ep1, bf2f(h0.y), bf2f(a0.y)));
        af[2] = (short)f2bf(fmaf(ep1, bf2f(h0.z), bf2f(a0.z)));
        af[3] = (short)f2bf(fmaf(ep1, bf2f(h0.w), bf2f(a0.w)));
        af[4] = (short)f2bf(fmaf(ep1, bf2f(h1.x), bf2f(a1.x)));
        af[5] = (short)f2bf(fmaf(ep1, bf2f(h1.y), bf2f(a1.y)));
        af[6] = (short)f2bf(fmaf(ep1, bf2f(h1.z), bf2f(a1.z)));
        af[7] = (short)f2bf(fmaf(ep1, bf2f(h1.w), bf2f(a1.w)));

#pragma unroll
        for (int nt = 0; nt < 8; ++nt) {
            bf16x8 bf = *(const bf16x8*)(wbf + (size_t)(nt * 16 + l16) * D + k0);
            acc[nt] = __builtin_amdgcn_mfma_f32_16x16x32_bf16(bf, af, acc[nt], 0, 0, 0);
        }
    }

    if (node < N_NODES) {
#pragma unroll
        for (int nt = 0; nt < 8; ++nt) {
            int c0 = nt * 16 + kg * 4;
            float4 bv = *(const float4*)(bias + c0);
            vf4 xv = __builtin_nontemporal_load((const vf4*)(x + (size_t)node * D + c0));
            vf4 o;
            o.x = acc[nt][0] + bv.x + xv.x;
            o.y = acc[nt][1] + bv.y + xv.y;
            o.z = acc[nt][2] + bv.z + xv.z;
            o.w = acc[nt][3] + bv.w + xv.w;
            __builtin_nontemporal_store(o, (vf4*)(out + (size_t)node * D + c0));
        }
    }
}

extern "C" void kernel_launch(void* const* d_in, const int* in_sizes, int n_in,
                              void* d_out, int out_size, void* d_ws, size_t ws_size,
                              hipStream_t stream)
{
    const float* x     = (const float*)d_in[0];
    const void*  ei    = d_in[1];
    const float* gamma = (const float*)d_in[2];
    const float* beta  = (const float*)d_in[3];
    const float* W     = (const float*)d_in[4];
    const float* bias  = (const float*)d_in[5];
    const float* eps_p = (const float*)d_in[6];
    float* out = (float*)d_out;

    char* ws = (char*)d_ws;
    size_t off = 0;
    ushort_t* hb      = (ushort_t*)(ws + off); off += (size_t)N_NODES * D * 2;       // 25.6 MB
    ushort_t* aggrb   = (ushort_t*)(ws + off); off += (size_t)N_NODES * D * 2;       // 25.6 MB
    int*      bucket  = (int*)(ws + off);      off += (size_t)N_NODES * NSLOT * 4;   // 19.2 MB
    ushort_t* wbf     = (ushort_t*)(ws + off); off += (size_t)D * D * 2;             //  32 KB
    int*      ovf     = (int*)(ws + off);      off += (size_t)OVF_MAX * 2 * 4;       //  32 KB
    int*      ovf_cnt = (int*)(ws + off);      off += 4;

    (void)hipMemsetAsync(bucket, 0, (size_t)N_NODES * NSLOT * 4, stream);  // zero cnts
    (void)hipMemsetAsync(ovf_cnt, 0, 4, stream);
    build_wbf_ln_kernel<<<NB_EDGE + NB_WBF + NB_LN, 256, 0, stream>>>(
        ei, bucket, ovf, ovf_cnt, W, wbf, x, gamma, beta, hb);
    bucket_segsum_kernel<<<N_NODES / 4, 256, 0, stream>>>(hb, bucket, ovf, ovf_cnt, aggrb);
    gemm_mfma_kernel<<<(N_NODES + 63) / 64, 256, 0, stream>>>(hb, aggrb, x, wbf, bias, eps_p, out);
}